// Round 21
// baseline (163.009 us; speedup 1.0000x reference)
//
#include <hip/hip_runtime.h>
#include <hip/hip_bf16.h>
#include <cstdint>
#include <cstddef>

#define BS 8
#define SEQ 1024
#define DMODEL 512
#define NHEADS 8
#define DHEAD 64
#define QBLK 16
#define PPAD 1032     // dense-fallback P stride (shorts)

typedef float f32x4 __attribute__((ext_vector_type(4)));
typedef short bf16x8 __attribute__((ext_vector_type(8)));

static __device__ __forceinline__ unsigned short f2bf(float v) {
    __hip_bfloat16 hb = __float2bfloat16(v);
    return *reinterpret_cast<unsigned short*>(&hb);
}

// ---------------------------------------------------------------------------
// f32 -> bf16 conversion pre-pass (weights only now; 4 jobs)
// ---------------------------------------------------------------------------
struct CvtJob { const float* s; unsigned short* d; int n4; };

__global__ __launch_bounds__(256) void cvt_many(
    CvtJob j0, CvtJob j1, CvtJob j2, CvtJob j3)
{
    CvtJob j;
    switch (blockIdx.y) {
        case 0: j = j0; break; case 1: j = j1; break;
        case 2: j = j2; break; default: j = j3; break;
    }
    for (int i = blockIdx.x * 256 + threadIdx.x; i < j.n4; i += gridDim.x * 256) {
        const float4 f = ((const float4*)j.s)[i];
        uint2 u;
        u.x = (unsigned)f2bf(f.x) | ((unsigned)f2bf(f.y) << 16);
        u.y = (unsigned)f2bf(f.z) | ((unsigned)f2bf(f.w) << 16);
        ((uint2*)j.d)[i] = u;
    }
}

// ---------------------------------------------------------------------------
// bf16 MFMA GEMM (r6-validated core). Modes 0/1/2/3 epilogues unchanged.
// NEW (r21): af32=1 -> A is f32 in global; staged via register conversion +
// swizzled ds_write_b128 into the SAME LDS image the gload_lds path produces
// (LDS[r*64 + 8*(c8 ^ (r&7))] = global chunk c8), so the MFMA read path is
// byte-identical. B always stages via global_load_lds (bf16 weights).
// ---------------------------------------------------------------------------
struct GArgs { const void* A; const unsigned short* W;
               const float* bias; void* C; void* C2; float scale;
               int mode; int af32; };

__global__ __launch_bounds__(256) void gemm_mfma(GArgs g0, GArgs g1, GArgs g2) {
    __shared__ __align__(16) unsigned short As[64 * 64];
    __shared__ __align__(16) unsigned short Bs[128 * 64];

    const GArgs g = (blockIdx.z == 0) ? g0 : ((blockIdx.z == 1) ? g1 : g2);
    const int tid = threadIdx.x;
    const int w = tid >> 6, l = tid & 63, lr = l & 15, lg = l >> 4;
    const int bm = blockIdx.y * 64, bn = blockIdx.x * 128;
    const int mrow = (w & 1) * 32, ncol = (w >> 1) * 64;

    f32x4 acc[2][4];
#pragma unroll
    for (int mt = 0; mt < 2; ++mt)
#pragma unroll
        for (int nt = 0; nt < 4; ++nt) acc[mt][nt] = (f32x4)0.f;

    for (int k0 = 0; k0 < DMODEL; k0 += 64) {
        // ---- B staging first (DMA flies under A's VALU conversion) ----
#pragma unroll
        for (int i = 0; i < 4; ++i) {
            const int rbase = i * 32 + w * 8;
            const int r = rbase + (l >> 3);
            const unsigned short* src = g.W + (size_t)(bn + r) * DMODEL + k0
                                        + 8 * ((l & 7) ^ (r & 7));
            __builtin_amdgcn_global_load_lds((const unsigned int*)src,
                                             (unsigned int*)&Bs[rbase * 64], 16, 0, 0);
        }
        // ---- A staging ----
        if (g.af32) {
            // row sr2 = tid>>2 (0..63), col-group tid&3 (16 f32 = 64 B, coalesced)
            const int sr2 = tid >> 2;
            const int cg = tid & 3;
            const float* ap = (const float*)g.A + (size_t)(bm + sr2) * DMODEL
                              + k0 + cg * 16;
            const float4 fA = ((const float4*)ap)[0];
            const float4 fB = ((const float4*)ap)[1];
            const float4 fC = ((const float4*)ap)[2];
            const float4 fD = ((const float4*)ap)[3];
            unsigned short tmp[16];
            tmp[0] = f2bf(fA.x); tmp[1] = f2bf(fA.y); tmp[2] = f2bf(fA.z); tmp[3] = f2bf(fA.w);
            tmp[4] = f2bf(fB.x); tmp[5] = f2bf(fB.y); tmp[6] = f2bf(fB.z); tmp[7] = f2bf(fB.w);
            tmp[8] = f2bf(fC.x); tmp[9] = f2bf(fC.y); tmp[10] = f2bf(fC.z); tmp[11] = f2bf(fC.w);
            tmp[12] = f2bf(fD.x); tmp[13] = f2bf(fD.y); tmp[14] = f2bf(fD.z); tmp[15] = f2bf(fD.w);
            const int gch = cg * 2;   // global 8-elem chunk index of tmp[0..7]
            *(uint4*)&As[sr2 * 64 + 8 * ((gch    ) ^ (sr2 & 7))] = *(const uint4*)&tmp[0];
            *(uint4*)&As[sr2 * 64 + 8 * ((gch + 1) ^ (sr2 & 7))] = *(const uint4*)&tmp[8];
        } else {
#pragma unroll
            for (int i = 0; i < 2; ++i) {
                const int rbase = i * 32 + w * 8;
                const int r = rbase + (l >> 3);
                const unsigned short* src = (const unsigned short*)g.A
                                            + (size_t)(bm + r) * DMODEL + k0
                                            + 8 * ((l & 7) ^ (r & 7));
                __builtin_amdgcn_global_load_lds((const unsigned int*)src,
                                                 (unsigned int*)&As[rbase * 64], 16, 0, 0);
            }
        }
        __syncthreads();   // drains gload DMA (vmcnt) + ds_writes (lgkmcnt)
#pragma unroll
        for (int kk = 0; kk < 2; ++kk) {
            bf16x8 av[2], bv[4];
#pragma unroll
            for (int mt = 0; mt < 2; ++mt) {
                const int ra = mrow + mt * 16 + lr;
                av[mt] = *(const bf16x8*)&As[ra * 64 + 8 * ((kk * 4 + lg) ^ (ra & 7))];
            }
#pragma unroll
            for (int nt = 0; nt < 4; ++nt) {
                const int rb = ncol + nt * 16 + lr;
                bv[nt] = *(const bf16x8*)&Bs[rb * 64 + 8 * ((kk * 4 + lg) ^ (rb & 7))];
            }
#pragma unroll
            for (int mt = 0; mt < 2; ++mt)
#pragma unroll
                for (int nt = 0; nt < 4; ++nt)
                    acc[mt][nt] = __builtin_amdgcn_mfma_f32_16x16x32_bf16(
                        av[mt], bv[nt], acc[mt][nt], 0, 0, 0);
        }
        __syncthreads();
    }

    if (g.mode == 0) {
        float* C = (float*)g.C;
#pragma unroll
        for (int mt = 0; mt < 2; ++mt)
#pragma unroll
        for (int nt = 0; nt < 4; ++nt)
#pragma unroll
        for (int j = 0; j < 4; ++j) {
            const int r = bm + mrow + mt * 16 + lg * 4 + j;
            const int c = bn + ncol + nt * 16 + lr;
            C[(size_t)r * DMODEL + c] = acc[mt][nt][j] * g.scale
                                        + (g.bias ? g.bias[c] : 0.f);
        }
    } else {
        if (g.mode == 1 || g.mode == 3) {
            unsigned short* C = (unsigned short*)g.C;
#pragma unroll
            for (int mt = 0; mt < 2; ++mt)
#pragma unroll
            for (int nt = 0; nt < 4; ++nt)
#pragma unroll
            for (int j = 0; j < 4; ++j) {
                const int r = bm + mrow + mt * 16 + lg * 4 + j;
                const int c = bn + ncol + nt * 16 + lr;
                const float v = acc[mt][nt][j] * g.scale + (g.bias ? g.bias[c] : 0.f);
                const int b = r >> 10, ll = r & (SEQ - 1);
                const int h = c >> 6, dd = c & 63;
                C[((size_t)(b * NHEADS + h) * SEQ + ll) * DHEAD + dd] = f2bf(v);
            }
        }
        if (g.mode == 2 || g.mode == 3) {
            unsigned short* C = (unsigned short*)((g.mode == 3) ? g.C2 : g.C);
#pragma unroll
            for (int mt = 0; mt < 2; ++mt)
#pragma unroll
            for (int nt = 0; nt < 4; ++nt) {
                const int c = bn + ncol + nt * 16 + lr;
                const int h = c >> 6, dd = c & 63;
                const int r0 = bm + mrow + mt * 16 + lg * 4;
                const int b = r0 >> 10, l0 = r0 & (SEQ - 1);
                unsigned short tmp[4];
#pragma unroll
                for (int j = 0; j < 4; ++j)
                    tmp[j] = f2bf(acc[mt][nt][j] * g.scale + (g.bias ? g.bias[c] : 0.f));
                uint2 u;
                u.x = (unsigned)tmp[0] | ((unsigned)tmp[1] << 16);
                u.y = (unsigned)tmp[2] | ((unsigned)tmp[3] << 16);
                *(uint2*)&C[((size_t)(b * NHEADS + h) * DHEAD + dd) * SEQ + l0] = u;
            }
        }
    }
}

// ---------------------------------------------------------------------------
// Fused MFMA sparsemax attention — r20 FROZEN (best passing: attn ~102 us).
// ---------------------------------------------------------------------------
__global__ __launch_bounds__(256, 3) void attn_mfma(
    const unsigned short* __restrict__ Q, const unsigned short* __restrict__ K,
    const unsigned short* __restrict__ Vt, const unsigned short* __restrict__ Vn,
    unsigned short* __restrict__ R)
{
    __shared__ __align__(16) unsigned char pool[33024];   // Ks[2][8192] u16 | P[16][PPAD]
    __shared__ __align__(16) float clist[QBLK][66];
    __shared__ __align__(16) unsigned short cidx[QBLK][66];
    __shared__ int cnt_s[QBLK];
    __shared__ __align__(16) float red_m[QBLK][4];
    __shared__ __align__(16) float red_s[2][QBLK][4];
    __shared__ __align__(16) float red_c[2][QBLK][4];
    __shared__ float tau_s[QBLK];

    unsigned short* Ks = (unsigned short*)pool;                       // [2][128*64]
    unsigned short (*P)[PPAD] = (unsigned short (*)[PPAD])pool;       // fallback

    const int tid = threadIdx.x;
    const int w = tid >> 6, l = tid & 63, lr = l & 15, lg = l >> 4;

    // XCD-aware decode (r5-validated)
    const int flat = blockIdx.x;
    const int nid = (flat & 7) * 512 + (flat >> 3);
    const int q0 = (nid & 63) * QBLK;
    const int h = (nid >> 6) & (NHEADS - 1);
    const int b = nid >> 9;

    const size_t base = (size_t)(b * NHEADS + h) * SEQ * DHEAD;
    const unsigned short* Qp = Q + base;
    const unsigned short* Kp = K + base;

    // Q frags (B-operand): Q[q0+lr][lg*8+i (+32)], pre-scaled 1/8
    const bf16x8 aq0 = *(const bf16x8*)(Qp + (size_t)(q0 + lr) * DHEAD + lg * 8);
    const bf16x8 aq1 = *(const bf16x8*)(Qp + (size_t)(q0 + lr) * DHEAD + 32 + lg * 8);

    // ---- staged QK^T over 8 chunks of 128 keys, double-buffered ----
#define STAGE(CH, BUF)                                                         \
    {                                                                          \
        _Pragma("unroll")                                                      \
        for (int i = 0; i < 4; ++i) {                                          \
            const int rbase = i * 32 + w * 8;                                  \
            const int r = rbase + (l >> 3);                                    \
            const unsigned short* src = Kp + (size_t)((CH) * 128 + r) * DHEAD  \
                                        + 8 * ((l & 7) ^ (r & 7));             \
            __builtin_amdgcn_global_load_lds((const unsigned int*)src,         \
                (unsigned int*)&Ks[(BUF) * 8192 + rbase * 64], 16, 0, 0);      \
        }                                                                      \
    }

    f32x4 acc[16];
#pragma unroll
    for (int a = 0; a < 16; ++a) acc[a] = (f32x4)0.f;

    STAGE(0, 0)
    __syncthreads();
#pragma unroll
    for (int c = 0; c < 8; ++c) {
        const int buf = c & 1;
        if (c + 1 < 8) STAGE(c + 1, buf ^ 1)
        const unsigned short* kb = Ks + buf * 8192;
#pragma unroll
        for (int tt = 0; tt < 2; ++tt) {
            const int ra = w * 32 + tt * 16 + lr;
            const bf16x8 k0 = *(const bf16x8*)&kb[ra * 64 + 8 * ((0 + lg) ^ (ra & 7))];
            const bf16x8 k1 = *(const bf16x8*)&kb[ra * 64 + 8 * ((4 + lg) ^ (ra & 7))];
            acc[2 * c + tt] = __builtin_amdgcn_mfma_f32_16x16x32_bf16(
                k0, aq0, acc[2 * c + tt], 0, 0, 0);
            acc[2 * c + tt] = __builtin_amdgcn_mfma_f32_16x16x32_bf16(
                k1, aq1, acc[2 * c + tt], 0, 0, 0);
        }
        __syncthreads();
    }
#undef STAGE
    // lane (lr,lg) holds S[q-row q0+lr][key (a>>1)*128 + w*32 + (a&1)*16 + lg*4 + j]

    // ---- row max ----
    f32x4 m4 = acc[0];
#pragma unroll
    for (int a = 1; a < 16; ++a) {
        m4[0] = fmaxf(m4[0], acc[a][0]); m4[1] = fmaxf(m4[1], acc[a][1]);
        m4[2] = fmaxf(m4[2], acc[a][2]); m4[3] = fmaxf(m4[3], acc[a][3]);
    }
    float m = fmaxf(fmaxf(m4[0], m4[1]), fmaxf(m4[2], m4[3]));
    m = fmaxf(m, __shfl_xor(m, 16));
    m = fmaxf(m, __shfl_xor(m, 32));
    if (lg == 0) red_m[lr][w] = m;

    // clear candidate lists (values AND indices — padding must be harmless)
    for (int i = tid; i < QBLK * 66; i += 256) {
        (&clist[0][0])[i] = -3.0e38f;
        (&cidx[0][0])[i] = 0;
    }
    if (tid < QBLK) cnt_s[tid] = 0;
    __syncthreads();

    const float4 rm4 = *(const float4*)red_m[lr];
    const float rmax = fmaxf(fmaxf(rm4.x, rm4.y), fmaxf(rm4.z, rm4.w));
    float tau = rmax - 1.0f;
    const float thr = tau;   // support subset of {z > rowmax-1}

    // ---- candidate compaction with indices (cap 64) ----
#pragma unroll
    for (int a = 0; a < 16; ++a)
#pragma unroll
        for (int j = 0; j < 4; ++j) {
            const float z = acc[a][j];
            if (z > thr) {
                const int pos = atomicAdd(&cnt_s[lr], 1);
                if (pos < 64) {
                    clist[lr][pos] = z;
                    cidx[lr][pos] = (unsigned short)((a >> 1) * 128 + w * 32
                                                     + (a & 1) * 16 + lg * 4 + j);
                }
            }
        }
    __syncthreads();

    const bool anyfull = __any(cnt_s[lr] > 64);   // block-uniform

    if (!anyfull) {
        // ---- PREFETCH first-16 candidate V-rows (tau-independent indices) ----
        const int r = tid >> 4;
        const int dt = tid & 15;
        const unsigned short* Vrow = Vn + base + dt * 4;
        uint2 pvx[16];
#pragma unroll
        for (int k = 0; k < 16; ++k)
            pvx[k] = *(const uint2*)(Vrow + (size_t)cidx[r][k] * DHEAD);

        // ---- FAST: wave-local Newton on shared candidate list ----
        const f32x4* clp = (const f32x4*)&clist[lr][lg * 16];
        const f32x4 cd0 = clp[0], cd1 = clp[1], cd2 = clp[2], cd3 = clp[3];
        for (int it = 0; it < 16; ++it) {
            float s = 0.f, c = 0.f;
#pragma unroll
            for (int i = 0; i < 4; ++i) {
                const float z0 = cd0[i], z1 = cd1[i], z2 = cd2[i], z3 = cd3[i];
                if (z0 > tau) { s += z0; c += 1.f; }
                if (z1 > tau) { s += z1; c += 1.f; }
                if (z2 > tau) { s += z2; c += 1.f; }
                if (z3 > tau) { s += z3; c += 1.f; }
            }
            s += __shfl_xor(s, 16); c += __shfl_xor(c, 16);
            s += __shfl_xor(s, 32); c += __shfl_xor(c, 32);
            const float tn = (s - 1.f) / c;   // c >= 1 (tau < row max)
            float delta = tn - tau;
            tau = tn;
            delta = fmaxf(delta, __shfl_xor(delta, 1));
            delta = fmaxf(delta, __shfl_xor(delta, 2));
            delta = fmaxf(delta, __shfl_xor(delta, 4));
            delta = fmaxf(delta, __shfl_xor(delta, 8));
            if (delta < 1e-5f) break;   // wave-uniform trajectory
        }
        if (w == 0 && lg == 0) tau_s[lr] = tau;
        __syncthreads();

        // ---- sparse gather PV: first 16 from regs, branch-free remainder ----
        const float taur = tau_s[r];
        const int cntc = cnt_s[r];
        f32x4 o = (f32x4)0.f;
#pragma unroll
        for (int k = 0; k < 16; ++k) {
            const float wgt = fmaxf(clist[r][k] - taur, 0.f);
            o[0] += wgt * __uint_as_float(pvx[k].x << 16);
            o[1] += wgt * __uint_as_float(pvx[k].x & 0xffff0000u);
            o[2] += wgt * __uint_as_float(pvx[k].y << 16);
            o[3] += wgt * __uint_as_float(pvx[k].y & 0xffff0000u);
        }
        if (cntc > 16) {
            const int nIt = (cntc + 7) & ~7;
            for (int i = 16; i < nIt; i += 8) {
#pragma unroll
                for (int k = 0; k < 8; ++k) {
                    const float z = clist[r][i + k];
                    const uint2 v = *(const uint2*)(Vrow + (size_t)cidx[r][i + k] * DHEAD);
                    const float wgt = fmaxf(z - taur, 0.f);
                    o[0] += wgt * __uint_as_float(v.x << 16);
                    o[1] += wgt * __uint_as_float(v.x & 0xffff0000u);
                    o[2] += wgt * __uint_as_float(v.y << 16);
                    o[3] += wgt * __uint_as_float(v.y & 0xffff0000u);
                }
            }
        }
        unsigned short t4[4];
#pragma unroll
        for (int j = 0; j < 4; ++j) t4[j] = f2bf(o[j]);
        uint2 u;
        u.x = (unsigned)t4[0] | ((unsigned)t4[1] << 16);
        u.y = (unsigned)t4[2] | ((unsigned)t4[3] << 16);
        *(uint2*)&R[((size_t)b * SEQ + q0 + r) * DMODEL + h * DHEAD + dt * 4] = u;
        return;
    }

    // ================= DENSE FALLBACK (acc still live; P overlays Ks) =======
    for (int it = 0; it < 16; ++it) {
        const int bb = (it + 1) & 1;
        float s = 0.f, c = 0.f;
#pragma unroll
        for (int a = 0; a < 16; ++a)
#pragma unroll
            for (int j = 0; j < 4; ++j) {
                const float z = acc[a][j];
                if (z > tau) { s += z; c += 1.f; }
            }
        s += __shfl_xor(s, 16); c += __shfl_xor(c, 16);
        s += __shfl_xor(s, 32); c += __shfl_xor(c, 32);
        if (lg == 0) { red_s[bb][lr][w] = s; red_c[bb][lr][w] = c; }
        __syncthreads();
        const float4 s4 = *(const float4*)red_s[bb][lr];
        const float4 c4 = *(const float4*)red_c[bb][lr];
        const float st = (s4.x + s4.y) + (s4.z + s4.w);
        const float ct = (c4.x + c4.y) + (c4.z + c4.w);
        const float tn = (st - 1.f) / ct;
        float delta = tn - tau;
        tau = tn;
        delta = fmaxf(delta, __shfl_xor(delta, 1));
        delta = fmaxf(delta, __shfl_xor(delta, 2));
        delta = fmaxf(delta, __shfl_xor(delta, 4));
        delta = fmaxf(delta, __shfl_xor(delta, 8));
        if (delta < 1e-5f) break;
    }
    __syncthreads();   // all waves past K reads before P writes

#pragma unroll
    for (int a = 0; a < 16; ++a)
#pragma unroll
        for (int jp = 0; jp < 2; ++jp) {
            const unsigned lo = f2bf(fmaxf(acc[a][2 * jp] - tau, 0.f));
            const unsigned hi = f2bf(fmaxf(acc[a][2 * jp + 1] - tau, 0.f));
            const int key = (a >> 1) * 128 + w * 32 + (a & 1) * 16 + lg * 4 + 2 * jp;
            *(unsigned*)&P[lr][key] = lo | (hi << 16);
        }
    __syncthreads();

    const int dcol = w * 16;
    const unsigned short* VtP = Vt + ((size_t)(b * NHEADS + h) * DHEAD + dcol + lr) * SEQ
                                + lg * 8;
    f32x4 o = (f32x4)0.f;
    bf16x8 vb0 = *(const bf16x8*)(VtP + 0 * 32);
    bf16x8 vb1 = *(const bf16x8*)(VtP + 1 * 32);
    bf16x8 vb2 = *(const bf16x8*)(VtP + 2 * 32);
    bf16x8 vb3 = *(const bf16x8*)(VtP + 3 * 32);
#define PV_STEP(KT, VREG)                                                      \
    {                                                                          \
        const bf16x8 pa = *(const bf16x8*)&P[lr][(KT) * 32 + lg * 8];          \
        o = __builtin_amdgcn_mfma_f32_16x16x32_bf16(pa, VREG, o, 0, 0, 0);     \
        if ((KT) + 4 < 32) VREG = *(const bf16x8*)(VtP + ((KT) + 4) * 32);     \
    }
    for (int kt = 0; kt < 32; kt += 4) {
        PV_STEP(kt + 0, vb0)
        PV_STEP(kt + 1, vb1)
        PV_STEP(kt + 2, vb2)
        PV_STEP(kt + 3, vb3)
    }
#undef PV_STEP

#pragma unroll
    for (int j = 0; j < 4; ++j)
        R[((size_t)b * SEQ + q0 + lg * 4 + j) * DMODEL + h * DHEAD + dcol + lr] =
            f2bf(o[j]);
}

extern "C" void kernel_launch(void* const* d_in, const int* in_sizes, int n_in,
                              void* d_out, int out_size, void* d_ws, size_t ws_size,
                              hipStream_t stream) {
    const float* h_q = (const float*)d_in[0];
    const float* h_k = (const float*)d_in[1];
    const float* h_v = (const float*)d_in[2];
    const float* Wq  = (const float*)d_in[3];
    const float* Wk  = (const float*)d_in[4];
    const float* Wv  = (const float*)d_in[5];
    const float* bv  = (const float*)d_in[6];
    const float* Wf  = (const float*)d_in[7];
    const float* bf  = (const float*)d_in[8];
    float* out = (float*)d_out;

    const size_t perT = (size_t)BS * SEQ * DMODEL;   // 4,194,304 elements
    const size_t wN = (size_t)DMODEL * DMODEL;
    unsigned short* Qws  = (unsigned short*)d_ws;    // head layout, pre-scaled 1/8
    unsigned short* Kws  = Qws + perT;               // head layout
    unsigned short* Vtw  = Kws + perT;               // transposed [b][h][d][l]
    unsigned short* Vnw  = Vtw + perT;               // normal [b][h][l][d]
    unsigned short* Rws  = Vnw + perT;
    unsigned short* Wqb  = Rws + perT;
    unsigned short* Wkb  = Wqb + wN;
    unsigned short* Wvb  = Wkb + wN;
    unsigned short* Wfb  = Wvb + wN;

    // 1) convert WEIGHTS to bf16 (inputs are converted in-GEMM now)
    {
        CvtJob j0{Wq, Wqb, (int)(wN / 4)};
        CvtJob j1{Wk, Wkb, (int)(wN / 4)};
        CvtJob j2{Wv, Wvb, (int)(wN / 4)};
        CvtJob j3{Wf, Wfb, (int)(wN / 4)};
        cvt_many<<<dim3(64, 4), 256, 0, stream>>>(j0, j1, j2, j3);
    }

    // 2) fused Q/K/V projections, A = raw f32 inputs (converted in staging)
    {
        GArgs gq{h_q, Wqb, nullptr, Qws, nullptr, 0.125f, 1, 1};
        GArgs gk{h_k, Wkb, nullptr, Kws, nullptr, 1.0f, 1, 1};
        GArgs gv{h_v, Wvb, bv,      Vnw, Vtw,     1.0f, 3, 1};
        gemm_mfma<<<dim3(DMODEL / 128, BS * SEQ / 64, 3), 256, 0, stream>>>(gq, gk, gv);
    }

    // 3) fused attention (r20 frozen)
    attn_mfma<<<dim3(BS * NHEADS * (SEQ / QBLK)), 256, 0, stream>>>(Qws, Kws, Vtw, Vnw, Rws);

    // 4) output projection (A = bf16 Rws)
    {
        GArgs gf{Rws, Wfb, bf, out, nullptr, 1.0f, 0, 0};
        gemm_mfma<<<dim3(DMODEL / 128, BS * SEQ / 64, 1), 256, 0, stream>>>(gf, gf, gf);
    }
}

// Round 22
// 157.670 us; speedup vs baseline: 1.0339x; 1.0339x over previous
//
#include <hip/hip_runtime.h>
#include <hip/hip_bf16.h>
#include <cstdint>
#include <cstddef>

#define BS 8
#define SEQ 1024
#define DMODEL 512
#define NHEADS 8
#define DHEAD 64
#define QBLK 16
#define PPAD 1032     // dense-fallback P stride (shorts)

typedef float f32x4 __attribute__((ext_vector_type(4)));
typedef short bf16x8 __attribute__((ext_vector_type(8)));

static __device__ __forceinline__ unsigned short f2bf(float v) {
    __hip_bfloat16 hb = __float2bfloat16(v);
    return *reinterpret_cast<unsigned short*>(&hb);
}

// ---------------------------------------------------------------------------
// f32 -> bf16 conversion pre-pass (7 jobs)
// ---------------------------------------------------------------------------
struct CvtJob { const float* s; unsigned short* d; int n4; };

__global__ __launch_bounds__(256) void cvt_many(
    CvtJob j0, CvtJob j1, CvtJob j2, CvtJob j3, CvtJob j4, CvtJob j5, CvtJob j6)
{
    CvtJob j;
    switch (blockIdx.y) {
        case 0: j = j0; break; case 1: j = j1; break; case 2: j = j2; break;
        case 3: j = j3; break; case 4: j = j4; break; case 5: j = j5; break;
        default: j = j6; break;
    }
    for (int i = blockIdx.x * 256 + threadIdx.x; i < j.n4; i += gridDim.x * 256) {
        const float4 f = ((const float4*)j.s)[i];
        uint2 u;
        u.x = (unsigned)f2bf(f.x) | ((unsigned)f2bf(f.y) << 16);
        u.y = (unsigned)f2bf(f.z) | ((unsigned)f2bf(f.w) << 16);
        ((uint2*)j.d)[i] = u;
    }
}

// ---------------------------------------------------------------------------
// bf16 MFMA GEMM (r6-validated, unchanged). Modes 0/1/2/3.
// ---------------------------------------------------------------------------
struct GArgs { const unsigned short* A; const unsigned short* W;
               const float* bias; void* C; void* C2; float scale; int mode; };

__global__ __launch_bounds__(256) void gemm_mfma(GArgs g0, GArgs g1, GArgs g2) {
    __shared__ __align__(16) unsigned short As[64 * 64];
    __shared__ __align__(16) unsigned short Bs[128 * 64];

    const GArgs g = (blockIdx.z == 0) ? g0 : ((blockIdx.z == 1) ? g1 : g2);
    const int tid = threadIdx.x;
    const int w = tid >> 6, l = tid & 63, lr = l & 15, lg = l >> 4;
    const int bm = blockIdx.y * 64, bn = blockIdx.x * 128;
    const int mrow = (w & 1) * 32, ncol = (w >> 1) * 64;

    f32x4 acc[2][4];
#pragma unroll
    for (int mt = 0; mt < 2; ++mt)
#pragma unroll
        for (int nt = 0; nt < 4; ++nt) acc[mt][nt] = (f32x4)0.f;

    for (int k0 = 0; k0 < DMODEL; k0 += 64) {
#pragma unroll
        for (int i = 0; i < 2; ++i) {
            const int rbase = i * 32 + w * 8;
            const int r = rbase + (l >> 3);
            const unsigned short* src = g.A + (size_t)(bm + r) * DMODEL + k0
                                        + 8 * ((l & 7) ^ (r & 7));
            __builtin_amdgcn_global_load_lds((const unsigned int*)src,
                                             (unsigned int*)&As[rbase * 64], 16, 0, 0);
        }
#pragma unroll
        for (int i = 0; i < 4; ++i) {
            const int rbase = i * 32 + w * 8;
            const int r = rbase + (l >> 3);
            const unsigned short* src = g.W + (size_t)(bn + r) * DMODEL + k0
                                        + 8 * ((l & 7) ^ (r & 7));
            __builtin_amdgcn_global_load_lds((const unsigned int*)src,
                                             (unsigned int*)&Bs[rbase * 64], 16, 0, 0);
        }
        __syncthreads();
#pragma unroll
        for (int kk = 0; kk < 2; ++kk) {
            bf16x8 av[2], bv[4];
#pragma unroll
            for (int mt = 0; mt < 2; ++mt) {
                const int ra = mrow + mt * 16 + lr;
                av[mt] = *(const bf16x8*)&As[ra * 64 + 8 * ((kk * 4 + lg) ^ (ra & 7))];
            }
#pragma unroll
            for (int nt = 0; nt < 4; ++nt) {
                const int rb = ncol + nt * 16 + lr;
                bv[nt] = *(const bf16x8*)&Bs[rb * 64 + 8 * ((kk * 4 + lg) ^ (rb & 7))];
            }
#pragma unroll
            for (int mt = 0; mt < 2; ++mt)
#pragma unroll
                for (int nt = 0; nt < 4; ++nt)
                    acc[mt][nt] = __builtin_amdgcn_mfma_f32_16x16x32_bf16(
                        av[mt], bv[nt], acc[mt][nt], 0, 0, 0);
        }
        __syncthreads();
    }

    if (g.mode == 0) {
        float* C = (float*)g.C;
#pragma unroll
        for (int mt = 0; mt < 2; ++mt)
#pragma unroll
        for (int nt = 0; nt < 4; ++nt)
#pragma unroll
        for (int j = 0; j < 4; ++j) {
            const int r = bm + mrow + mt * 16 + lg * 4 + j;
            const int c = bn + ncol + nt * 16 + lr;
            C[(size_t)r * DMODEL + c] = acc[mt][nt][j] * g.scale
                                        + (g.bias ? g.bias[c] : 0.f);
        }
    } else {
        if (g.mode == 1 || g.mode == 3) {
            unsigned short* C = (unsigned short*)g.C;
#pragma unroll
            for (int mt = 0; mt < 2; ++mt)
#pragma unroll
            for (int nt = 0; nt < 4; ++nt)
#pragma unroll
            for (int j = 0; j < 4; ++j) {
                const int r = bm + mrow + mt * 16 + lg * 4 + j;
                const int c = bn + ncol + nt * 16 + lr;
                const float v = acc[mt][nt][j] * g.scale + (g.bias ? g.bias[c] : 0.f);
                const int b = r >> 10, ll = r & (SEQ - 1);
                const int h = c >> 6, dd = c & 63;
                C[((size_t)(b * NHEADS + h) * SEQ + ll) * DHEAD + dd] = f2bf(v);
            }
        }
        if (g.mode == 2 || g.mode == 3) {
            unsigned short* C = (unsigned short*)((g.mode == 3) ? g.C2 : g.C);
#pragma unroll
            for (int mt = 0; mt < 2; ++mt)
#pragma unroll
            for (int nt = 0; nt < 4; ++nt) {
                const int c = bn + ncol + nt * 16 + lr;
                const int h = c >> 6, dd = c & 63;
                const int r0 = bm + mrow + mt * 16 + lg * 4;
                const int b = r0 >> 10, l0 = r0 & (SEQ - 1);
                unsigned short tmp[4];
#pragma unroll
                for (int j = 0; j < 4; ++j)
                    tmp[j] = f2bf(acc[mt][nt][j] * g.scale + (g.bias ? g.bias[c] : 0.f));
                uint2 u;
                u.x = (unsigned)tmp[0] | ((unsigned)tmp[1] << 16);
                u.y = (unsigned)tmp[2] | ((unsigned)tmp[3] << 16);
                *(uint2*)&C[((size_t)(b * NHEADS + h) * DHEAD + dd) * SEQ + l0] = u;
            }
        }
    }
}

// ---------------------------------------------------------------------------
// Fused MFMA sparsemax attention (r20 = r19 + V-gather PREFETCH before Newton).
// Gather indices are tau-independent, so the first 16 candidate V-rows are
// loaded into a statically-indexed register array BEFORE the Newton loop;
// Newton's VALU iterations hide the L2 gather latency. MACs over all 16
// prefetched slots are unconditional (pads: z=-3e38 -> weight 0, idx=0 ->
// harmless V[0]); cnt>16 remainder uses the r19 branch-free loop.
// Everything else r19/r13-verbatim.
// ---------------------------------------------------------------------------
__global__ __launch_bounds__(256, 3) void attn_mfma(
    const unsigned short* __restrict__ Q, const unsigned short* __restrict__ K,
    const unsigned short* __restrict__ Vt, const unsigned short* __restrict__ Vn,
    unsigned short* __restrict__ R)
{
    __shared__ __align__(16) unsigned char pool[33024];   // Ks[2][8192] u16 | P[16][PPAD]
    __shared__ __align__(16) float clist[QBLK][66];
    __shared__ __align__(16) unsigned short cidx[QBLK][66];
    __shared__ int cnt_s[QBLK];
    __shared__ __align__(16) float red_m[QBLK][4];
    __shared__ __align__(16) float red_s[2][QBLK][4];
    __shared__ __align__(16) float red_c[2][QBLK][4];
    __shared__ float tau_s[QBLK];

    unsigned short* Ks = (unsigned short*)pool;                       // [2][128*64]
    unsigned short (*P)[PPAD] = (unsigned short (*)[PPAD])pool;       // fallback

    const int tid = threadIdx.x;
    const int w = tid >> 6, l = tid & 63, lr = l & 15, lg = l >> 4;

    // XCD-aware decode (r5-validated)
    const int flat = blockIdx.x;
    const int nid = (flat & 7) * 512 + (flat >> 3);
    const int q0 = (nid & 63) * QBLK;
    const int h = (nid >> 6) & (NHEADS - 1);
    const int b = nid >> 9;

    const size_t base = (size_t)(b * NHEADS + h) * SEQ * DHEAD;
    const unsigned short* Qp = Q + base;
    const unsigned short* Kp = K + base;

    // Q frags (B-operand): Q[q0+lr][lg*8+i (+32)], pre-scaled 1/8
    const bf16x8 aq0 = *(const bf16x8*)(Qp + (size_t)(q0 + lr) * DHEAD + lg * 8);
    const bf16x8 aq1 = *(const bf16x8*)(Qp + (size_t)(q0 + lr) * DHEAD + 32 + lg * 8);

    // ---- staged QK^T over 8 chunks of 128 keys, double-buffered ----
#define STAGE(CH, BUF)                                                         \
    {                                                                          \
        _Pragma("unroll")                                                      \
        for (int i = 0; i < 4; ++i) {                                          \
            const int rbase = i * 32 + w * 8;                                  \
            const int r = rbase + (l >> 3);                                    \
            const unsigned short* src = Kp + (size_t)((CH) * 128 + r) * DHEAD  \
                                        + 8 * ((l & 7) ^ (r & 7));             \
            __builtin_amdgcn_global_load_lds((const unsigned int*)src,         \
                (unsigned int*)&Ks[(BUF) * 8192 + rbase * 64], 16, 0, 0);      \
        }                                                                      \
    }

    f32x4 acc[16];
#pragma unroll
    for (int a = 0; a < 16; ++a) acc[a] = (f32x4)0.f;

    STAGE(0, 0)
    __syncthreads();
#pragma unroll
    for (int c = 0; c < 8; ++c) {
        const int buf = c & 1;
        if (c + 1 < 8) STAGE(c + 1, buf ^ 1)
        const unsigned short* kb = Ks + buf * 8192;
#pragma unroll
        for (int tt = 0; tt < 2; ++tt) {
            const int ra = w * 32 + tt * 16 + lr;
            const bf16x8 k0 = *(const bf16x8*)&kb[ra * 64 + 8 * ((0 + lg) ^ (ra & 7))];
            const bf16x8 k1 = *(const bf16x8*)&kb[ra * 64 + 8 * ((4 + lg) ^ (ra & 7))];
            acc[2 * c + tt] = __builtin_amdgcn_mfma_f32_16x16x32_bf16(
                k0, aq0, acc[2 * c + tt], 0, 0, 0);
            acc[2 * c + tt] = __builtin_amdgcn_mfma_f32_16x16x32_bf16(
                k1, aq1, acc[2 * c + tt], 0, 0, 0);
        }
        __syncthreads();
    }
#undef STAGE
    // lane (lr,lg) holds S[q-row q0+lr][key (a>>1)*128 + w*32 + (a&1)*16 + lg*4 + j]

    // ---- row max ----
    f32x4 m4 = acc[0];
#pragma unroll
    for (int a = 1; a < 16; ++a) {
        m4[0] = fmaxf(m4[0], acc[a][0]); m4[1] = fmaxf(m4[1], acc[a][1]);
        m4[2] = fmaxf(m4[2], acc[a][2]); m4[3] = fmaxf(m4[3], acc[a][3]);
    }
    float m = fmaxf(fmaxf(m4[0], m4[1]), fmaxf(m4[2], m4[3]));
    m = fmaxf(m, __shfl_xor(m, 16));
    m = fmaxf(m, __shfl_xor(m, 32));
    if (lg == 0) red_m[lr][w] = m;

    // clear candidate lists (values AND indices — padding must be harmless)
    for (int i = tid; i < QBLK * 66; i += 256) {
        (&clist[0][0])[i] = -3.0e38f;
        (&cidx[0][0])[i] = 0;
    }
    if (tid < QBLK) cnt_s[tid] = 0;
    __syncthreads();

    const float4 rm4 = *(const float4*)red_m[lr];
    const float rmax = fmaxf(fmaxf(rm4.x, rm4.y), fmaxf(rm4.z, rm4.w));
    float tau = rmax - 1.0f;
    const float thr = tau;   // support subset of {z > rowmax-1}

    // ---- candidate compaction with indices (cap 64) ----
#pragma unroll
    for (int a = 0; a < 16; ++a)
#pragma unroll
        for (int j = 0; j < 4; ++j) {
            const float z = acc[a][j];
            if (z > thr) {
                const int pos = atomicAdd(&cnt_s[lr], 1);
                if (pos < 64) {
                    clist[lr][pos] = z;
                    cidx[lr][pos] = (unsigned short)((a >> 1) * 128 + w * 32
                                                     + (a & 1) * 16 + lg * 4 + j);
                }
            }
        }
    __syncthreads();

    const bool anyfull = __any(cnt_s[lr] > 64);   // block-uniform

    if (!anyfull) {
        // ---- PREFETCH: issue first-16 candidate V-row loads NOW (indices
        // are tau-independent) so they fly under the Newton iterations. ----
        const int r = tid >> 4;
        const int dt = tid & 15;
        const unsigned short* Vrow = Vn + base + dt * 4;
        uint2 pvx[16];
#pragma unroll
        for (int k = 0; k < 16; ++k)
            pvx[k] = *(const uint2*)(Vrow + (size_t)cidx[r][k] * DHEAD);

        // ---- FAST: wave-local Newton on shared candidate list ----
        const f32x4* clp = (const f32x4*)&clist[lr][lg * 16];
        const f32x4 cd0 = clp[0], cd1 = clp[1], cd2 = clp[2], cd3 = clp[3];
        for (int it = 0; it < 16; ++it) {
            float s = 0.f, c = 0.f;
#pragma unroll
            for (int i = 0; i < 4; ++i) {
                const float z0 = cd0[i], z1 = cd1[i], z2 = cd2[i], z3 = cd3[i];
                if (z0 > tau) { s += z0; c += 1.f; }
                if (z1 > tau) { s += z1; c += 1.f; }
                if (z2 > tau) { s += z2; c += 1.f; }
                if (z3 > tau) { s += z3; c += 1.f; }
            }
            s += __shfl_xor(s, 16); c += __shfl_xor(c, 16);
            s += __shfl_xor(s, 32); c += __shfl_xor(c, 32);
            const float tn = (s - 1.f) / c;   // c >= 1 (tau < row max)
            float delta = tn - tau;
            tau = tn;
            delta = fmaxf(delta, __shfl_xor(delta, 1));
            delta = fmaxf(delta, __shfl_xor(delta, 2));
            delta = fmaxf(delta, __shfl_xor(delta, 4));
            delta = fmaxf(delta, __shfl_xor(delta, 8));
            if (delta < 1e-5f) break;   // wave-uniform trajectory
        }
        if (w == 0 && lg == 0) tau_s[lr] = tau;
        __syncthreads();

        // ---- sparse gather PV: first 16 from regs (unconditional — pads
        // carry weight 0), branch-free remainder loop for cnt > 16 ----
        const float taur = tau_s[r];
        const int cntc = cnt_s[r];
        f32x4 o = (f32x4)0.f;
#pragma unroll
        for (int k = 0; k < 16; ++k) {
            const float wgt = fmaxf(clist[r][k] - taur, 0.f);
            o[0] += wgt * __uint_as_float(pvx[k].x << 16);
            o[1] += wgt * __uint_as_float(pvx[k].x & 0xffff0000u);
            o[2] += wgt * __uint_as_float(pvx[k].y << 16);
            o[3] += wgt * __uint_as_float(pvx[k].y & 0xffff0000u);
        }
        if (cntc > 16) {
            const int nIt = (cntc + 7) & ~7;
            for (int i = 16; i < nIt; i += 8) {
#pragma unroll
                for (int k = 0; k < 8; ++k) {
                    const float z = clist[r][i + k];
                    const uint2 v = *(const uint2*)(Vrow + (size_t)cidx[r][i + k] * DHEAD);
                    const float wgt = fmaxf(z - taur, 0.f);
                    o[0] += wgt * __uint_as_float(v.x << 16);
                    o[1] += wgt * __uint_as_float(v.x & 0xffff0000u);
                    o[2] += wgt * __uint_as_float(v.y << 16);
                    o[3] += wgt * __uint_as_float(v.y & 0xffff0000u);
                }
            }
        }
        unsigned short t4[4];
#pragma unroll
        for (int j = 0; j < 4; ++j) t4[j] = f2bf(o[j]);
        uint2 u;
        u.x = (unsigned)t4[0] | ((unsigned)t4[1] << 16);
        u.y = (unsigned)t4[2] | ((unsigned)t4[3] << 16);
        *(uint2*)&R[((size_t)b * SEQ + q0 + r) * DMODEL + h * DHEAD + dt * 4] = u;
        return;
    }

    // ================= DENSE FALLBACK (acc still live; P overlays Ks) =======
    for (int it = 0; it < 16; ++it) {
        const int bb = (it + 1) & 1;
        float s = 0.f, c = 0.f;
#pragma unroll
        for (int a = 0; a < 16; ++a)
#pragma unroll
            for (int j = 0; j < 4; ++j) {
                const float z = acc[a][j];
                if (z > tau) { s += z; c += 1.f; }
            }
        s += __shfl_xor(s, 16); c += __shfl_xor(c, 16);
        s += __shfl_xor(s, 32); c += __shfl_xor(c, 32);
        if (lg == 0) { red_s[bb][lr][w] = s; red_c[bb][lr][w] = c; }
        __syncthreads();
        const float4 s4 = *(const float4*)red_s[bb][lr];
        const float4 c4 = *(const float4*)red_c[bb][lr];
        const float st = (s4.x + s4.y) + (s4.z + s4.w);
        const float ct = (c4.x + c4.y) + (c4.z + c4.w);
        const float tn = (st - 1.f) / ct;
        float delta = tn - tau;
        tau = tn;
        delta = fmaxf(delta, __shfl_xor(delta, 1));
        delta = fmaxf(delta, __shfl_xor(delta, 2));
        delta = fmaxf(delta, __shfl_xor(delta, 4));
        delta = fmaxf(delta, __shfl_xor(delta, 8));
        if (delta < 1e-5f) break;
    }
    __syncthreads();   // all waves past K reads before P writes

#pragma unroll
    for (int a = 0; a < 16; ++a)
#pragma unroll
        for (int jp = 0; jp < 2; ++jp) {
            const unsigned lo = f2bf(fmaxf(acc[a][2 * jp] - tau, 0.f));
            const unsigned hi = f2bf(fmaxf(acc[a][2 * jp + 1] - tau, 0.f));
            const int key = (a >> 1) * 128 + w * 32 + (a & 1) * 16 + lg * 4 + 2 * jp;
            *(unsigned*)&P[lr][key] = lo | (hi << 16);
        }
    __syncthreads();

    const int dcol = w * 16;
    const unsigned short* VtP = Vt + ((size_t)(b * NHEADS + h) * DHEAD + dcol + lr) * SEQ
                                + lg * 8;
    f32x4 o = (f32x4)0.f;
    bf16x8 vb0 = *(const bf16x8*)(VtP + 0 * 32);
    bf16x8 vb1 = *(const bf16x8*)(VtP + 1 * 32);
    bf16x8 vb2 = *(const bf16x8*)(VtP + 2 * 32);
    bf16x8 vb3 = *(const bf16x8*)(VtP + 3 * 32);
#define PV_STEP(KT, VREG)                                                      \
    {                                                                          \
        const bf16x8 pa = *(const bf16x8*)&P[lr][(KT) * 32 + lg * 8];          \
        o = __builtin_amdgcn_mfma_f32_16x16x32_bf16(pa, VREG, o, 0, 0, 0);     \
        if ((KT) + 4 < 32) VREG = *(const bf16x8*)(VtP + ((KT) + 4) * 32);     \
    }
    for (int kt = 0; kt < 32; kt += 4) {
        PV_STEP(kt + 0, vb0)
        PV_STEP(kt + 1, vb1)
        PV_STEP(kt + 2, vb2)
        PV_STEP(kt + 3, vb3)
    }
#undef PV_STEP

#pragma unroll
    for (int j = 0; j < 4; ++j)
        R[((size_t)b * SEQ + q0 + lg * 4 + j) * DMODEL + h * DHEAD + dcol + lr] =
            f2bf(o[j]);
}

extern "C" void kernel_launch(void* const* d_in, const int* in_sizes, int n_in,
                              void* d_out, int out_size, void* d_ws, size_t ws_size,
                              hipStream_t stream) {
    const float* h_q = (const float*)d_in[0];
    const float* h_k = (const float*)d_in[1];
    const float* h_v = (const float*)d_in[2];
    const float* Wq  = (const float*)d_in[3];
    const float* Wk  = (const float*)d_in[4];
    const float* Wv  = (const float*)d_in[5];
    const float* bv  = (const float*)d_in[6];
    const float* Wf  = (const float*)d_in[7];
    const float* bf  = (const float*)d_in[8];
    float* out = (float*)d_out;

    const size_t perT = (size_t)BS * SEQ * DMODEL;   // 4,194,304 elements
    const size_t wN = (size_t)DMODEL * DMODEL;
    unsigned short* hq_b = (unsigned short*)d_ws;
    unsigned short* hk_b = hq_b + perT;
    unsigned short* hv_b = hk_b + perT;
    unsigned short* Qws  = hv_b + perT;              // head layout, pre-scaled 1/8
    unsigned short* Kws  = Qws + perT;               // head layout
    unsigned short* Vtw  = Kws + perT;               // transposed [b][h][d][l]
    unsigned short* Vnw  = Vtw + perT;               // normal [b][h][l][d]
    unsigned short* Rws  = Vnw + perT;
    unsigned short* Wqb  = Rws + perT;
    unsigned short* Wkb  = Wqb + wN;
    unsigned short* Wvb  = Wkb + wN;
    unsigned short* Wfb  = Wvb + wN;

    // 1) convert inputs + weights to bf16
    {
        CvtJob j0{h_q, hq_b, (int)(perT / 4)};
        CvtJob j1{h_k, hk_b, (int)(perT / 4)};
        CvtJob j2{h_v, hv_b, (int)(perT / 4)};
        CvtJob j3{Wq, Wqb, (int)(wN / 4)};
        CvtJob j4{Wk, Wkb, (int)(wN / 4)};
        CvtJob j5{Wv, Wvb, (int)(wN / 4)};
        CvtJob j6{Wf, Wfb, (int)(wN / 4)};
        cvt_many<<<dim3(512, 7), 256, 0, stream>>>(j0, j1, j2, j3, j4, j5, j6);
    }

    // 2) fused Q/K/V projections (V in both layouts)
    {
        GArgs gq{hq_b, Wqb, nullptr, Qws, nullptr, 0.125f, 1};
        GArgs gk{hk_b, Wkb, nullptr, Kws, nullptr, 1.0f, 1};
        GArgs gv{hv_b, Wvb, bv,      Vnw, Vtw,     1.0f, 3};
        gemm_mfma<<<dim3(DMODEL / 128, BS * SEQ / 64, 3), 256, 0, stream>>>(gq, gk, gv);
    }

    // 3) fused attention (r19 + V-gather prefetch under Newton)
    attn_mfma<<<dim3(BS * NHEADS * (SEQ / QBLK)), 256, 0, stream>>>(Qws, Kws, Vtw, Vnw, Rws);

    // 4) output projection
    {
        GArgs gf{Rws, Wfb, bf, out, nullptr, 1.0f, 0};
        gemm_mfma<<<dim3(DMODEL / 128, BS * SEQ / 64, 1), 256, 0, stream>>>(gf, gf, gf);
    }
}